// Round 1
// baseline (104.585 us; speedup 1.0000x reference)
//
#include <hip/hip_runtime.h>
#include <math.h>

#define NUM_CLASSES 1000
#define NV4 250            // float4 chunks per row (1000 floats)
#define BATCH 16384
#define NBLOCKS (BATCH / 4)

// exp2 native op (v_exp_f32 IS exp2 on gfx950); guard the builtin.
#if __has_builtin(__builtin_amdgcn_exp2f)
#define EXP2F(x) __builtin_amdgcn_exp2f(x)
#else
#define EXP2F(x) exp2f(x)
#endif

// R7: branchless restructure. Theory: row_loss (~40us, hidden below the
// 41.3us fill rows in top-5) runs at 1.6 TB/s vs 6.3 achievable -> it is
// VALU-issue/divergence-bound, NOT memory-bound. Changes vs R5 best:
//  - wave-max butterfly FIRST, then one exp pass with the final max:
//    removes the online-softmax rescale (12 exps + 12 shuffles/wave) and
//    enables se += exp2(fma(x, log2e, -m*log2e)) = 1 VALU + 1 trans.
//  - include-then-subtract the true class: w(c) = rcp(1.0) = 1.0 exactly,
//    so accumulate ws/tw over ALL valid k, then ws -= lc, tw -= 1 once.
//    Kills the per-element divergent if(k==c)/else (exec-mask ping-pong
//    16x per lane: both paths always execute since exactly 1 lane owns c).
//  - float-domain distance with abs input-modifier:
//    w = rcp(1.0 + |base + (256i+e)|) -> 2 VALU + 1 trans (no int abs/cvt).
//  - padding masks hoisted to i==3 only (lane-uniform lane<58); i=0..2 are
//    completely condition-free (k <= 767 < 1000 statically).
// Per element: ~15 VALU + 2 trans + branches  ->  6 VALU + 2 trans.
// Predicted: row_loss ~40 -> ~18-25us, dur_us 92.2 -> ~72-80us.
__global__ __launch_bounds__(256) void row_loss_kernel(
    const float* __restrict__ logits,
    const int* __restrict__ targets,
    float* __restrict__ partials) {
  const int wave = threadIdx.x >> 6;   // 0..3
  const int lane = threadIdx.x & 63;
  const int b = blockIdx.x * 4 + wave;

  const float4* row = (const float4*)(logits + (size_t)b * NUM_CLASSES);
  const int c = __builtin_amdgcn_readfirstlane(targets[b]);  // wave-uniform

  float4 v[4];
  v[0] = row[lane];
  v[1] = row[lane + 64];
  v[2] = row[lane + 128];
  v[3] = (lane < 58) ? row[lane + 192]
                     : make_float4(-INFINITY, -INFINITY, -INFINITY, -INFINITY);

  // per-lane max, then wave max (6 shfl+fmax). Pads are -inf: harmless.
  float m = -INFINITY;
#pragma unroll
  for (int i = 0; i < 4; ++i)
    m = fmaxf(m, fmaxf(fmaxf(v[i].x, v[i].y), fmaxf(v[i].z, v[i].w)));
#pragma unroll
  for (int o = 32; o > 0; o >>= 1) m = fmaxf(m, __shfl_xor(m, o));

  // extract x_c once per wave (uniform index -> cndmask chain + 1 shfl).
  // c<1000 -> owning lane = (c>>2)&63 is always <58, so its value is real.
  {
    // nothing: block kept for readability of the extraction below
  }
  const int ic = c >> 8;          // which v[i]
  const int ec = c & 3;           // which component
  const int cl = (c >> 2) & 63;   // which lane
  float4 vc = v[0];
  if (ic == 1) vc = v[1];
  if (ic == 2) vc = v[2];
  if (ic == 3) vc = v[3];
  float xc = vc.x;
  if (ec == 1) xc = vc.y;
  if (ec == 2) xc = vc.z;
  if (ec == 3) xc = vc.w;
  const float lc = __shfl(xc, cl);

  const float L2E = 1.4426950408889634f;
  const float nym = m * (-L2E);              // -m*log2e
  const float base = (float)(lane * 4) - (float)c;  // k - c for e=0,i=0

  float se = 0.f;   // sum exp(x - m)  via exp2(fma(x,L2E,nym))
  float ws = 0.f;   // sum_{valid k} x_k / (|k-c|+1)   (includes k==c, w=1)
  float tw = 0.f;   // sum_{valid k} 1 / (|k-c|+1)     (includes k==c, w=1)
#pragma unroll
  for (int i = 0; i < 4; ++i) {
    const float xs[4] = {v[i].x, v[i].y, v[i].z, v[i].w};
#pragma unroll
    for (int e = 0; e < 4; ++e) {
      const float x = xs[e];
      se += EXP2F(__builtin_fmaf(x, L2E, nym));   // pad: exp2(-inf) = 0
      const float d1 = 1.0f + __builtin_fabsf(base + (float)(256 * i + e));
      float w = __builtin_amdgcn_rcpf(d1);        // exact 1.0 at k==c
      float xw = x;
      if (i == 3) {                 // compile-time branch; lane-uniform mask
        const bool valid = (lane < 58);
        w  = valid ? w  : 0.f;      // pads must not count in tw
        xw = valid ? xw : 0.f;      // avoid 0 * -inf = NaN in ws
      }
      ws = __builtin_fmaf(w, xw, ws);
      tw += w;
    }
  }

  // plain sum butterfly (no online rescale needed: single global max).
#pragma unroll
  for (int o = 32; o > 0; o >>= 1) {
    se += __shfl_xor(se, o);
    ws += __shfl_xor(ws, o);
    tw += __shfl_xor(tw, o);
  }

  __shared__ float sw[4];
  if (lane == 0) {
    // remove the k==c contribution (exactly 1.0 * lc / 1.0):
    const float lse = m + 0.69314718055994531f * __log2f(se);
    sw[wave] = lse - (0.9f * lc + 0.1f * ((ws - lc) / (tw - 1.0f)));
  }
  __syncthreads();
  if (threadIdx.x == 0) {
    partials[blockIdx.x] = (sw[0] + sw[1]) + (sw[2] + sw[3]);
  }
}

// Reduce 4096 block-partials -> mean. 256 threads, 1024 float4 loads.
__global__ __launch_bounds__(256) void final_reduce_kernel(
    const float4* __restrict__ partials, float* __restrict__ out) {
  float s = 0.f;
#pragma unroll
  for (int i = 0; i < NBLOCKS / 4 / 256; ++i) {
    const float4 t = partials[threadIdx.x + 256 * i];
    s += (t.x + t.y) + (t.z + t.w);
  }
#pragma unroll
  for (int o = 32; o > 0; o >>= 1) s += __shfl_xor(s, o);
  __shared__ float sw[4];
  if ((threadIdx.x & 63) == 0) sw[threadIdx.x >> 6] = s;
  __syncthreads();
  if (threadIdx.x == 0) {
    out[0] = ((sw[0] + sw[1]) + (sw[2] + sw[3])) * (1.0f / (float)BATCH);
  }
}

extern "C" void kernel_launch(void* const* d_in, const int* in_sizes, int n_in,
                              void* d_out, int out_size, void* d_ws, size_t ws_size,
                              hipStream_t stream) {
  const float* logits = (const float*)d_in[0];
  const int* targets = (const int*)d_in[1];
  float* out = (float*)d_out;
  float* partials = (float*)d_ws;   // NBLOCKS floats = 16 KB scratch

  row_loss_kernel<<<NBLOCKS, 256, 0, stream>>>(logits, targets, partials);
  final_reduce_kernel<<<1, 256, 0, stream>>>((const float4*)partials, out);
}

// Round 2
// 93.199 us; speedup vs baseline: 1.1222x; 1.1222x over previous
//
#include <hip/hip_runtime.h>
#include <math.h>

#define NUM_CLASSES 1000
#define NV4 250            // float4 chunks per row (1000 floats)
#define BATCH 16384
#define NBLOCKS (BATCH / 4)

// One wave (64 lanes) per row, 4 rows per 256-thread block. Online-softmax:
// per-lane (max, sum-exp) built during the load pass, then ONE 6-step
// butterfly merges all five row statistics. Each block writes a single
// non-atomic partial (sum of its 4 row losses) — no atomics, no fences
// (R3/R4 measured: same-address device atomics ~13 ns each serialized;
// per-block __threadfence is worse). A tiny second kernel reduces 4096
// partials.
//
// R6 post-mortem: VALU-minimization (closed-form tw, float-domain distance,
// unconditional ws) REGRESSED +11 us.
// R7 post-mortem: branchless restructure (wave-max-first, include-subtract,
// exp2/fma, float-domain distance) REGRESSED +12.4 us. Mechanism: extra live
// state (x_c extraction chain) pushed VGPRs past the 64-reg occupancy step
// (8 -> 4 waves/SIMD, m69), halving in-flight bytes under HBM queuing.
//
// Timing decomposition (R0/R1 evidence): top-5 cutoff is ~41.2 us (256 MiB
// harness poison fills); row_loss NEVER appears in top-5 => it is <41 us.
// Only consistent split: dur_us = 2 x 41.4 us fixed fills + kernels.
// This R5 structure: kernels ~= 9.4 us vs 10.4 us HBM streaming floor for
// the 65.5 MB logits read => AT the memory roofline (partial L3 assist).
// This file restores the best-measured version (92.2 us).
__global__ __launch_bounds__(256) void row_loss_kernel(
    const float* __restrict__ logits,
    const int* __restrict__ targets,
    float* __restrict__ partials) {
  const int wave = threadIdx.x >> 6;   // 0..3
  const int lane = threadIdx.x & 63;
  const int b = blockIdx.x * 4 + wave;

  const float4* row = (const float4*)(logits + (size_t)b * NUM_CLASSES);
  const int c = __builtin_amdgcn_readfirstlane(targets[b]);  // wave-uniform

  float4 v[4];
#pragma unroll
  for (int i = 0; i < 4; ++i) {
    const int j = lane + 64 * i;
    if (j < NV4) v[i] = row[j];
    else v[i] = make_float4(-INFINITY, -INFINITY, -INFINITY, -INFINITY);
  }

  float m = -INFINITY;
#pragma unroll
  for (int i = 0; i < 4; ++i)
    m = fmaxf(m, fmaxf(fmaxf(v[i].x, v[i].y), fmaxf(v[i].z, v[i].w)));

  float se = 0.f;   // sum exp(x - m)   (per-lane m for now)
  float ws = 0.f;   // sum_{k != c} x_k / (|k-c|+1)
  float tw = 0.f;   // sum_{k != c} 1 / (|k-c|+1)
  float lc = 0.f;   // x_c
#pragma unroll
  for (int i = 0; i < 4; ++i) {
    const float xs[4] = {v[i].x, v[i].y, v[i].z, v[i].w};
    const int k0 = (lane + 64 * i) * 4;
#pragma unroll
    for (int e = 0; e < 4; ++e) {
      const int k = k0 + e;
      const float x = xs[e];
      se += __expf(x - m);                 // pad: exp(-inf) = 0
      if (k < NUM_CLASSES) {
        if (k == c) {
          lc = x;
        } else {
          const float w = __builtin_amdgcn_rcpf((float)(abs(k - c) + 1));
          ws = fmaf(w, x, ws);
          tw += w;
        }
      }
    }
  }

  // single butterfly merging (m, se) online-softmax style + 3 plain sums
#pragma unroll
  for (int o = 32; o > 0; o >>= 1) {
    const float mo  = __shfl_xor(m, o);
    const float seo = __shfl_xor(se, o);
    const float wso = __shfl_xor(ws, o);
    const float two = __shfl_xor(tw, o);
    const float lco = __shfl_xor(lc, o);
    const float nm = fmaxf(m, mo);
    se = se * __expf(m - nm) + seo * __expf(mo - nm);
    m = nm;
    ws += wso;
    tw += two;
    lc += lco;
  }

  __shared__ float sw[4];
  if (lane == 0) {
    // smoothing row of M sums to exactly 1.0 -> loss = lse - dot(M_row, x)
    sw[wave] = m + __logf(se) - (0.9f * lc + 0.1f * (ws / tw));
  }
  __syncthreads();
  if (threadIdx.x == 0) {
    partials[blockIdx.x] = (sw[0] + sw[1]) + (sw[2] + sw[3]);
  }
}

// Reduce 4096 block-partials -> mean. 256 threads, 1024 float4 loads.
__global__ __launch_bounds__(256) void final_reduce_kernel(
    const float4* __restrict__ partials, float* __restrict__ out) {
  float s = 0.f;
#pragma unroll
  for (int i = 0; i < NBLOCKS / 4 / 256; ++i) {
    const float4 t = partials[threadIdx.x + 256 * i];
    s += (t.x + t.y) + (t.z + t.w);
  }
#pragma unroll
  for (int o = 32; o > 0; o >>= 1) s += __shfl_xor(s, o);
  __shared__ float sw[4];
  if ((threadIdx.x & 63) == 0) sw[threadIdx.x >> 6] = s;
  __syncthreads();
  if (threadIdx.x == 0) {
    out[0] = ((sw[0] + sw[1]) + (sw[2] + sw[3])) * (1.0f / (float)BATCH);
  }
}

extern "C" void kernel_launch(void* const* d_in, const int* in_sizes, int n_in,
                              void* d_out, int out_size, void* d_ws, size_t ws_size,
                              hipStream_t stream) {
  const float* logits = (const float*)d_in[0];
  const int* targets = (const int*)d_in[1];
  float* out = (float*)d_out;
  float* partials = (float*)d_ws;   // NBLOCKS floats = 16 KB scratch

  row_loss_kernel<<<NBLOCKS, 256, 0, stream>>>(logits, targets, partials);
  final_reduce_kernel<<<1, 256, 0, stream>>>((const float4*)partials, out);
}